// Round 7
// baseline (182.443 us; speedup 1.0000x reference)
//
#include <hip/hip_runtime.h>
#include <stdint.h>

#define N_BOX 1024
#define C_CLS 80
#define B_IMG 4
#define K_PER 100
#define K_TOT 300
#define NEGF  (-1e30f)
#define NWORD 16                 // 1024 bits / 64
#define NCAND (C_CLS * K_PER)    // 8000 candidates per image
#define M_SEL 8192               // flat-index packing base for final top-k

// workspace layout (bytes)
#define OFF_SCOREST 0            // [B][C][N] f32          1,310,720
#define OFF_MASKS   1310720      // [B][N][NWORD] u64        524,288
#define OFF_SORTED  1835008      // [B*C][N] u64           2,621,440
#define OFF_NVALID  4456448      // [B*C] i32                  1,280
#define OFF_WSCORE  4457728      // [B*C][K_PER] f32         128,000
#define OFF_WSIDX   4585728      // [B*C][K_PER] i32         128,000

typedef unsigned long long u64;
typedef unsigned int u32;

// ---- monotone float <-> ordered-uint mapping (total order, bit-exact) ----
__device__ __forceinline__ u32 ford(float f) {
    u32 u = __float_as_uint(f);
    return (u & 0x80000000u) ? ~u : (u | 0x80000000u);
}
__device__ __forceinline__ float funord(u32 o) {
    u32 u = (o & 0x80000000u) ? (o ^ 0x80000000u) : ~o;
    return __uint_as_float(u);
}

// IoU matching the numpy/jax float32 arithmetic exactly: no fma contraction.
__device__ __forceinline__ float iou_f(float4 a, float4 b) {
#pragma clang fp contract(off)
    float y1a = fminf(a.x, a.z), y2a = fmaxf(a.x, a.z);
    float x1a = fminf(a.y, a.w), x2a = fmaxf(a.y, a.w);
    float y1b = fminf(b.x, b.z), y2b = fmaxf(b.x, b.z);
    float x1b = fminf(b.y, b.w), x2b = fmaxf(b.y, b.w);
    float ih = fminf(y2a, y2b) - fmaxf(y1a, y1b); ih = fmaxf(ih, 0.0f);
    float iw = fminf(x2a, x2b) - fmaxf(x1a, x1b); iw = fmaxf(iw, 0.0f);
    float inter = ih * iw;
    float aa = (y2a - y1a) * (x2a - x1a);
    float ab = (y2b - y1b) * (x2b - x1b);
    float uni = aa + ab - inter;
    uni = fmaxf(uni, 1e-12f);
    return inter / uni;
}

// ---------------------------------------------------------------------------
// Kernel A (fused prep): blocks [0,256): per-image IoU bitmask matrix
// (proven round-2/5/6 code). blocks [256,1536): transpose scores
// [B,N,C] -> [B,C,N] so sort blocks read contiguous rows.
// ---------------------------------------------------------------------------
__global__ __launch_bounds__(256) void prep_kernel(
        const float* __restrict__ scores,   // [B, N, C]
        const float* __restrict__ boxes,    // [B, N, 1, 4]
        u64*   __restrict__ masks,          // [B, N, NWORD]
        float* __restrict__ scoresT)        // [B, C, N]
{
    __shared__ float4 bx[N_BOX];            // 16 KB (mask path); reused as tile
    const int tid = threadIdx.x;

    if (blockIdx.x < 256) {
        const int b  = blockIdx.x >> 6;         // 4 images
        const int rg = blockIdx.x & 63;         // 64 row-groups of 16 rows
        for (int n = tid; n < N_BOX; n += 256)
            bx[n] = ((const float4*)boxes)[b * N_BOX + n];
        __syncthreads();

        const int r = tid >> 4;                 // local row 0..15
        const int w = tid & 15;                 // word 0..15
        const int i = rg * 16 + r;
        float4 a = bx[i];
        u64 m = 0;
        const int j0 = w * 64;
        for (int jj = 0; jj < 64; ++jj) {
            int j = j0 + jj;
            if (j != i && iou_f(a, bx[j]) > 0.5f) m |= (1ull << jj);
        }
        masks[((size_t)(b * N_BOX + i)) * NWORD + w] = m;
    } else {
        // transpose: 16x16 tiles; C=80 -> 5 tiles, N=1024 -> 64 tiles
        float* tile = (float*)bx;               // [16][17]
        const int t = blockIdx.x - 256;
        const int b  = t / 320;
        const int rm = t % 320;
        const int n0 = (rm / 5) * 16;
        const int c0 = (rm % 5) * 16;
        const int r = tid >> 4, cc = tid & 15;
        tile[r * 17 + cc] = scores[(size_t)(b * N_BOX + n0 + r) * C_CLS + c0 + cc];
        __syncthreads();
        scoresT[(size_t)(b * C_CLS + c0 + r) * N_BOX + n0 + cc] = tile[cc * 17 + r];
    }
}

// ---------------------------------------------------------------------------
// Kernel B: one block per (image,class) = 320 blocks x 256 threads.
// Coalesced float4 row load, stable-descending bitonic sort of 1024 packed
// keys in LDS, write sorted keys + nvalid to workspace.
// ---------------------------------------------------------------------------
__global__ __launch_bounds__(256) void sort_classes(
        const float* __restrict__ scoresT,  // [B, C, N]
        u64* __restrict__ sorted,           // [B*C, N]
        int* __restrict__ nvalid_arr)       // [B*C]
{
    __shared__ u64 key[N_BOX];              // 8 KB
    __shared__ int sh_nvalid;

    const int tid = threadIdx.x;
    const int blk = blockIdx.x;             // b*80 + c

    if (tid == 0) sh_nvalid = 0;
    __syncthreads();

    {   // coalesced float4 load of this class's 1024 scores
        const float4 s4 = ((const float4*)(scoresT + ((size_t)blk << 10)))[tid];
        float sv[4] = {s4.x, s4.y, s4.z, s4.w};
        int lv = 0;
        const int n0 = tid * 4;
        #pragma unroll
        for (int q = 0; q < 4; ++q) {
            bool valid = sv[q] > 0.001f;               // SCORE_THR
            float s = valid ? sv[q] : NEGF;
            key[n0 + q] = ((u64)ford(s) << 32) | (u32)(N_BOX - 1 - (n0 + q));
            lv += valid ? 1 : 0;
        }
        if (lv) atomicAdd(&sh_nvalid, lv);
    }
    __syncthreads();

    // bitonic sort, descending on packed key (proven round-2/5/6 network)
    for (int k = 2; k <= N_BOX; k <<= 1) {
        for (int j = k >> 1; j > 0; j >>= 1) {
            for (int i = tid; i < N_BOX; i += 256) {
                int ixj = i ^ j;
                if (ixj > i) {
                    u64 a = key[i], q = key[ixj];
                    if (((i & k) == 0) ? (a < q) : (a > q)) { key[i] = q; key[ixj] = a; }
                }
            }
            __syncthreads();
        }
    }

    u64* outk = sorted + ((size_t)blk << 10);
    for (int i = tid; i < N_BOX; i += 256) outk[i] = key[i];
    if (tid == 0) nvalid_arr[blk] = sh_nvalid;
}

// ---------------------------------------------------------------------------
// Kernel C: 4 classes per block (one wave each), 80 blocks x 256 threads.
// Proven round-6 batched greedy (4 mask rows per serial L2 round-trip),
// keys read coalesced from the sorted workspace. No __syncthreads at all.
// ---------------------------------------------------------------------------
__global__ __launch_bounds__(256) void greedy_classes(
        const u64* __restrict__ sorted,     // [B*C, N]
        const int* __restrict__ nvalid_arr, // [B*C]
        const u64* __restrict__ masks,      // [B, N, NWORD]
        float* __restrict__ ws_score,       // [B*C*K_PER]
        int*   __restrict__ ws_idx)         // [B*C*K_PER]
{
    __shared__ int kept_t[4][K_PER];

    const int tid = threadIdx.x;
    const int wv = tid >> 6;                // wave 0..3 = class slot
    const int lane = tid & 63;
    const int cls = blockIdx.x * 4 + wv;    // b*80 + c
    const int b = cls / C_CLS;

    const int w16 = lane & 15;
    const int rr = lane >> 4;               // which of 4 batch rows I load
    const u64* mrow = masks + (size_t)b * N_BOX * NWORD;
    const u64* ks = sorted + ((size_t)cls << 10);
    const int nvalid = nvalid_arr[cls];
    u64 sup = 0;                            // lanes 0..15 hold suppressed words
    int kept = 0;

    for (int bt = 0; bt < nvalid && kept < K_PER; bt += 64) {
        int t = bt + lane;
        bool in = t < nvalid;
        u64 kv = ks[t & (N_BOX - 1)];       // coalesced 512 B per window
        int idx = (N_BOX - 1) - (int)(u32)(kv & 0xFFFFFFFFu); // original box id
        u64 window = __ballot(in);
        while (window && kept < K_PER) {
            u64 supw = __shfl(sup, idx >> 6);
            bool sbit = (supw >> (idx & 63)) & 1ull;
            u64 alive = __ballot(in && !sbit) & window;
            if (!alive) break;
            // pick up to 4 leading alive candidates (all wave-uniform)
            int nb = 0, ts0 = 63, ts1 = 63, ts2 = 63, ts3 = 63;
            {
                u64 am = alive;
                ts0 = __ffsll((long long)am) - 1; am &= am - 1; nb = 1;
                if (am) { ts1 = __ffsll((long long)am) - 1; am &= am - 1; nb = 2; }
                if (am) { ts2 = __ffsll((long long)am) - 1; am &= am - 1; nb = 3; }
                if (am) { ts3 = __ffsll((long long)am) - 1; nb = 4; }
            }
            int bi0 = __shfl(idx, ts0), bi1 = __shfl(idx, ts1);
            int bi2 = __shfl(idx, ts2), bi3 = __shfl(idx, ts3);
            int bir = (rr == 0) ? bi0 : (rr == 1) ? bi1 : (rr == 2) ? bi2 : bi3;
            u64 myrow = 0;
            if (rr < nb) myrow = mrow[(size_t)bir * NWORD + w16];
            // progressive accept within the batch (greedy-exact)
            bool acc1 = false, acc2 = false, acc3 = false;
            if (nb > 1) {
                u64 w = __shfl(myrow, (bi1 >> 6));           // row0 words, lanes 0..15
                acc1 = !((w >> (bi1 & 63)) & 1ull);
            }
            if (nb > 2) {
                u64 w = __shfl(myrow, (bi2 >> 6));
                bool s2 = (w >> (bi2 & 63)) & 1ull;
                if (!s2 && acc1) {
                    u64 w2 = __shfl(myrow, 16 + (bi2 >> 6)); // row1 words
                    s2 = (w2 >> (bi2 & 63)) & 1ull;
                }
                acc2 = !s2;
            }
            if (nb > 3) {
                u64 w = __shfl(myrow, (bi3 >> 6));
                bool s3 = (w >> (bi3 & 63)) & 1ull;
                if (!s3 && acc1) {
                    u64 w2 = __shfl(myrow, 16 + (bi3 >> 6));
                    s3 = (w2 >> (bi3 & 63)) & 1ull;
                }
                if (!s3 && acc2) {
                    u64 w2 = __shfl(myrow, 32 + (bi3 >> 6)); // row2 words
                    s3 = (w2 >> (bi3 & 63)) & 1ull;
                }
                acc3 = !s3;
            }
            // commit accepted in order; OR their rows into sup
            int tsv[4] = {ts0, ts1, ts2, ts3};
            bool accv[4] = {true, acc1, acc2, acc3};
            #pragma unroll
            for (int r = 0; r < 4; ++r) {
                if (r < nb && accv[r] && kept < K_PER) {
                    if (lane == 0) kept_t[wv][kept] = bt + tsv[r];
                    kept++;
                    u64 w = __shfl(myrow, r * 16 + w16);
                    if (lane < NWORD) sup |= w;
                }
            }
            int tlast = tsv[nb - 1];
            window &= ~((2ull << tlast) - 1ull);
        }
    }

    // emit (same wave wrote kept_t -> LDS ordering within wave is safe;
    // kept was incremented uniformly by every lane)
    for (int i = lane; i < K_PER; i += 64) {
        int ob = cls * K_PER + i;
        if (i < kept) {
            u64 k = ks[kept_t[wv][i]];
            ws_score[ob] = funord((u32)(k >> 32));
            ws_idx[ob]   = (N_BOX - 1) - (int)(u32)(k & 0xFFFFFFFFu);
        } else {
            ws_score[ob] = NEGF;
            ws_idx[ob]   = 0;
        }
    }
}

// ---------------------------------------------------------------------------
// Kernel D: one block per image, 256 threads (round-6 proven, verbatim).
// ---------------------------------------------------------------------------
__global__ __launch_bounds__(256) void final_topk(
        const float* __restrict__ ws_score,
        const int*   __restrict__ ws_idx,
        const float* __restrict__ boxes,    // [B, N, 1, 4]
        float* __restrict__ out)
{
    __shared__ u32 skey[NCAND];             // 32 KB — high word of each key
    __shared__ u32 hist4[256 * 4];          // 4 KB — 4 bank-spread slots/bin
    __shared__ u64 list[512];
    __shared__ int sh_sel;
    __shared__ u32 sh_need;
    __shared__ int sh_cnt, sh_valid;

    const int tid = threadIdx.x;
    const int b = blockIdx.x;
    const int base = b * NCAND;

    if (tid == 0) { sh_cnt = 0; sh_valid = 0; }
    for (int i = tid; i < NCAND; i += 256)
        skey[i] = ford(ws_score[base + i]);
    list[tid] = 0;
    list[tid + 256] = 0;
    #pragma unroll
    for (int q = 0; q < 4; ++q) hist4[q * 256 + tid] = 0;
    __syncthreads();

    u64 prefix = 0;
    u32 need = K_TOT;
    const int rounds[6] = {7, 6, 5, 4, 1, 0};
    const int slot = tid & 3;

    for (int rd = 0; rd < 6; ++rd) {
        const int d = rounds[rd];
        for (int i = tid; i < NCAND; i += 256) {
            u64 k = ((u64)skey[i] << 32) | (u32)(M_SEL - 1 - i);
            // d==7 guard: shift by 64 is UB (the round-3/4 crash)
            bool match = (d == 7) || (((k ^ prefix) >> (8 * (d + 1))) == 0);
            if (match)
                atomicAdd(&hist4[(((u32)(k >> (8 * d)) & 0xFFu) << 2) | slot], 1u);
        }
        __syncthreads();
        if (tid < 64) {
            const int l = tid;
            u32 h[4];
            #pragma unroll
            for (int q = 0; q < 4; ++q) {
                int bin = 4 * l + q;
                h[q] = hist4[bin * 4 + 0] + hist4[bin * 4 + 1]
                     + hist4[bin * 4 + 2] + hist4[bin * 4 + 3];
                hist4[bin * 4 + 0] = 0; hist4[bin * 4 + 1] = 0;
                hist4[bin * 4 + 2] = 0; hist4[bin * 4 + 3] = 0;
            }
            u32 s3 = h[3], s2 = h[2] + s3, s1 = h[1] + s2, s0 = h[0] + s1;
            u32 tot = s0, S = tot;
            #pragma unroll
            for (int off = 1; off < 64; off <<= 1) {
                u32 t = __shfl(S, (l + off) & 63);
                if (l + off < 64) S += t;
            }
            u32 T = S - tot;                 // suffix over lanes > l
            u32 sv0 = s0 + T, sv1 = s1 + T, sv2 = s2 + T, sv3 = s3 + T;
            if (sv0 >= need && sv1 < need) { sh_sel = 4*l;     sh_need = need - sv1; }
            if (sv1 >= need && sv2 < need) { sh_sel = 4*l + 1; sh_need = need - sv2; }
            if (sv2 >= need && sv3 < need) { sh_sel = 4*l + 2; sh_need = need - sv3; }
            if (sv3 >= need && T   < need) { sh_sel = 4*l + 3; sh_need = need - T;   }
        }
        __syncthreads();
        prefix |= ((u64)(u32)sh_sel) << (8 * d);
        need = sh_need;
        __syncthreads();
    }

    for (int i = tid; i < NCAND; i += 256) {
        u64 k = ((u64)skey[i] << 32) | (u32)(M_SEL - 1 - i);
        if (k >= prefix) {
            int p = atomicAdd(&sh_cnt, 1);
            if (p < 512) list[p] = k;       // defensive clamp
        }
    }
    __syncthreads();

    for (int k2 = 2; k2 <= 512; k2 <<= 1) {
        for (int j = k2 >> 1; j > 0; j >>= 1) {
            for (int i = tid; i < 512; i += 256) {
                int ixj = i ^ j;
                if (ixj > i) {
                    u64 a = list[i], q = list[ixj];
                    if (((i & k2) == 0) ? (a < q) : (a > q)) { list[i] = q; list[ixj] = a; }
                }
            }
            __syncthreads();
        }
    }

    float* out_s = out;                         // [B,300]
    float* out_b = out + B_IMG * K_TOT;         // [B,300,4]
    float* out_c = out + B_IMG * K_TOT * 5;     // [B,300]
    float* out_n = out + B_IMG * K_TOT * 6;     // [B]

    for (int i = tid; i < K_TOT; i += 256) {
        u64 k = list[i];
        float s = funord((u32)(k >> 32));
        int flat = (M_SEL - 1) - (int)(u32)(k & 0xFFFFFFFFu);
        bool valid = s > (-5e29f);              // top_s > NEG/2
        float os = 0.0f, oc = 0.0f;
        float4 ob = make_float4(0.0f, 0.0f, 0.0f, 0.0f);
        if (valid && flat < NCAND) {
            int cc = flat / K_PER;
            int n  = ws_idx[base + flat];
            float4 bb = ((const float4*)boxes)[b * N_BOX + n];
            os = s;
            oc = (float)cc;
            ob.x = fminf(fmaxf(bb.x, 0.0f), 1.0f);
            ob.y = fminf(fmaxf(bb.y, 0.0f), 1.0f);
            ob.z = fminf(fmaxf(bb.z, 0.0f), 1.0f);
            ob.w = fminf(fmaxf(bb.w, 0.0f), 1.0f);
            atomicAdd(&sh_valid, 1);
        }
        out_s[b * K_TOT + i] = os;
        ((float4*)out_b)[b * K_TOT + i] = ob;
        out_c[b * K_TOT + i] = oc;
    }
    __syncthreads();
    if (tid == 0) out_n[b] = (float)sh_valid;
}

extern "C" void kernel_launch(void* const* d_in, const int* in_sizes, int n_in,
                              void* d_out, int out_size, void* d_ws, size_t ws_size,
                              hipStream_t stream) {
    const float* scores = (const float*)d_in[0];   // [4,1024,80]
    const float* boxes  = (const float*)d_in[1];   // [4,1024,1,4]

    char* ws = (char*)d_ws;                        // 4,713,728 B used
    float* scoresT    = (float*)(ws + OFF_SCOREST);
    u64*   masks      = (u64*)  (ws + OFF_MASKS);
    u64*   sorted     = (u64*)  (ws + OFF_SORTED);
    int*   nvalid_arr = (int*)  (ws + OFF_NVALID);
    float* ws_score   = (float*)(ws + OFF_WSCORE);
    int*   ws_idx     = (int*)  (ws + OFF_WSIDX);

    prep_kernel<<<dim3(256 + 1280), dim3(256), 0, stream>>>(scores, boxes, masks, scoresT);
    sort_classes<<<dim3(B_IMG * C_CLS), dim3(256), 0, stream>>>(scoresT, sorted, nvalid_arr);
    greedy_classes<<<dim3(B_IMG * C_CLS / 4), dim3(256), 0, stream>>>(
        sorted, nvalid_arr, masks, ws_score, ws_idx);
    final_topk<<<dim3(B_IMG), dim3(256), 0, stream>>>(
        ws_score, ws_idx, boxes, (float*)d_out);
}

// Round 8
// 166.399 us; speedup vs baseline: 1.0964x; 1.0964x over previous
//
#include <hip/hip_runtime.h>
#include <stdint.h>

#define N_BOX 1024
#define C_CLS 80
#define B_IMG 4
#define K_PER 100
#define K_TOT 300
#define NEGF  (-1e30f)
#define NWORD 16                 // 1024 bits / 64
#define NCAND (C_CLS * K_PER)    // 8000 candidates per image
#define M_SEL 8192               // flat-index packing base for final top-k

// workspace layout (bytes) — 2,091,008 total (4.7 MB proven safe round 7)
#define OFF_SCOREST 0            // [B][C][N] f32          1,310,720
#define OFF_MASKS   1310720      // [B][N][NWORD] u64        524,288
#define OFF_WSCORE  1835008      // [B*C][K_PER] f32         128,000
#define OFF_WSIDX   1963008      // [B*C][K_PER] i32         128,000

typedef unsigned long long u64;
typedef unsigned int u32;

// ---- monotone float <-> ordered-uint mapping (total order, bit-exact) ----
__device__ __forceinline__ u32 ford(float f) {
    u32 u = __float_as_uint(f);
    return (u & 0x80000000u) ? ~u : (u | 0x80000000u);
}
__device__ __forceinline__ float funord(u32 o) {
    u32 u = (o & 0x80000000u) ? (o ^ 0x80000000u) : ~o;
    return __uint_as_float(u);
}

// IoU matching the numpy/jax float32 arithmetic exactly: no fma contraction.
__device__ __forceinline__ float iou_f(float4 a, float4 b) {
#pragma clang fp contract(off)
    float y1a = fminf(a.x, a.z), y2a = fmaxf(a.x, a.z);
    float x1a = fminf(a.y, a.w), x2a = fmaxf(a.y, a.w);
    float y1b = fminf(b.x, b.z), y2b = fmaxf(b.x, b.z);
    float x1b = fminf(b.y, b.w), x2b = fmaxf(b.y, b.w);
    float ih = fminf(y2a, y2b) - fmaxf(y1a, y1b); ih = fmaxf(ih, 0.0f);
    float iw = fminf(x2a, x2b) - fmaxf(x1a, x1b); iw = fmaxf(iw, 0.0f);
    float inter = ih * iw;
    float aa = (y2a - y1a) * (x2a - x1a);
    float ab = (y2b - y1b) * (x2b - x1b);
    float uni = aa + ab - inter;
    uni = fmaxf(uni, 1e-12f);
    return inter / uni;
}

// ---------------------------------------------------------------------------
// Kernel A (fused prep, round-7 proven verbatim): blocks [0,256) = per-image
// IoU bitmask matrix; blocks [256,1536) = transpose scores [B,N,C]->[B,C,N].
// ---------------------------------------------------------------------------
__global__ __launch_bounds__(256) void prep_kernel(
        const float* __restrict__ scores,   // [B, N, C]
        const float* __restrict__ boxes,    // [B, N, 1, 4]
        u64*   __restrict__ masks,          // [B, N, NWORD]
        float* __restrict__ scoresT)        // [B, C, N]
{
    __shared__ float4 bx[N_BOX];            // 16 KB (mask path); reused as tile
    const int tid = threadIdx.x;

    if (blockIdx.x < 256) {
        const int b  = blockIdx.x >> 6;
        const int rg = blockIdx.x & 63;
        for (int n = tid; n < N_BOX; n += 256)
            bx[n] = ((const float4*)boxes)[b * N_BOX + n];
        __syncthreads();

        const int r = tid >> 4;
        const int w = tid & 15;
        const int i = rg * 16 + r;
        float4 a = bx[i];
        u64 m = 0;
        const int j0 = w * 64;
        for (int jj = 0; jj < 64; ++jj) {
            int j = j0 + jj;
            if (j != i && iou_f(a, bx[j]) > 0.5f) m |= (1ull << jj);
        }
        masks[((size_t)(b * N_BOX + i)) * NWORD + w] = m;
    } else {
        float* tile = (float*)bx;               // [16][17]
        const int t = blockIdx.x - 256;
        const int b  = t / 320;
        const int rm = t % 320;
        const int n0 = (rm / 5) * 16;
        const int c0 = (rm % 5) * 16;
        const int r = tid >> 4, cc = tid & 15;
        tile[r * 17 + cc] = scores[(size_t)(b * N_BOX + n0 + r) * C_CLS + c0 + cc];
        __syncthreads();
        scoresT[(size_t)(b * C_CLS + c0 + r) * N_BOX + n0 + cc] = tile[cc * 17 + r];
    }
}

// ---------------------------------------------------------------------------
// Kernel B: one block per (image, class-PAIR), 512 threads. Each half (256
// thr) sorts 1024 keys via register/shuffle bitonic: 4 consecutive elements
// per thread -> j in {1,2} in-register, j in {4..128} via __shfl_xor
// (partner lane j/4), only j in {256,512} through LDS (3 stages, 6 barriers
// instead of 55 barrier stages). Then waves 0/4 run 8-wide batched greedy
// (two independent mask-row loads per serial L2 round-trip).
// ---------------------------------------------------------------------------
__global__ __launch_bounds__(512) void nms_classes(
        const float* __restrict__ scoresT,  // [B, C, N]
        const u64*   __restrict__ masks,    // [B, N, NWORD]
        float* __restrict__ ws_score,       // [B*C*K_PER]
        int*   __restrict__ ws_idx)         // [B*C*K_PER]
{
    __shared__ u64 key[2][N_BOX];           // 16 KB
    __shared__ int kept_t[2][K_PER];
    __shared__ int sh_nvalid[2], sh_kept[2];

    const int tid  = threadIdx.x;
    const int half = tid >> 8;              // 0/1 = which class of the pair
    const int lt   = tid & 255;             // half-local thread id
    const int lane = tid & 63;
    const int b  = blockIdx.x / (C_CLS / 2);
    const int c  = (blockIdx.x % (C_CLS / 2)) * 2 + half;

    if (lt == 0) { sh_nvalid[half] = 0; sh_kept[half] = 0; }
    __syncthreads();

    // ---- load: thread lt owns elements v = lt*4+q (coalesced float4) ----
    u64 r[4];
    {
        const float4 s4 = ((const float4*)(scoresT + ((size_t)(b * C_CLS + c) << 10)))[lt];
        float sv[4] = {s4.x, s4.y, s4.z, s4.w};
        int lv = 0;
        #pragma unroll
        for (int q = 0; q < 4; ++q) {
            bool valid = sv[q] > 0.001f;               // SCORE_THR
            float s = valid ? sv[q] : NEGF;
            int v = lt * 4 + q;
            r[q] = ((u64)ford(s) << 32) | (u32)(N_BOX - 1 - v);  // stable ties
            lv += valid ? 1 : 0;
        }
        if (lv) atomicAdd(&sh_nvalid[half], lv);
    }

    // ---- bitonic sort, descending, 4 elems/thread ----
    #define CE(a, b, d) { u64 _mx = (a) > (b) ? (a) : (b); \
                          u64 _mn = (a) > (b) ? (b) : (a); \
                          (a) = (d) ? _mx : _mn; (b) = (d) ? _mn : _mx; }
    // k = 2: dir for pair(r0,r1) is desc (v&2==0), pair(r2,r3) asc
    CE(r[0], r[1], true); CE(r[2], r[3], false);

    for (int k = 4; k <= N_BOX; k <<= 1) {
        const bool d = ((lt & (k >> 2)) == 0);      // ((v&k)==0), q-independent
        for (int j = k >> 1; j > 0; j >>= 1) {
            if (j >= 256) {                          // cross-wave: LDS stage
                __syncthreads();                     // prior reads done
                #pragma unroll
                for (int q = 0; q < 4; ++q) key[half][lt * 4 + q] = r[q];
                __syncthreads();
                const bool upper = ((lt * 4) & j) != 0;
                #pragma unroll
                for (int q = 0; q < 4; ++q) {
                    u64 pv = key[half][(lt * 4 + q) ^ j];
                    u64 mx = r[q] > pv ? r[q] : pv;
                    u64 mn = r[q] > pv ? pv : r[q];
                    r[q] = (d != upper) ? mx : mn;
                }
            } else if (j >= 4) {                     // intra-wave: shuffle
                const int dl = j >> 2;
                const bool upper = (lane & dl) != 0;
                #pragma unroll
                for (int q = 0; q < 4; ++q) {
                    u64 pv = __shfl_xor(r[q], dl);
                    u64 mx = r[q] > pv ? r[q] : pv;
                    u64 mn = r[q] > pv ? pv : r[q];
                    r[q] = (d != upper) ? mx : mn;
                }
            } else if (j == 2) {                     // in-register
                CE(r[0], r[2], d); CE(r[1], r[3], d);
            } else {
                CE(r[0], r[1], d); CE(r[2], r[3], d);
            }
        }
    }
    #undef CE

    // final writeback (barrier: last LDS-stage reads of other threads' slots
    // must complete before we overwrite)
    __syncthreads();
    #pragma unroll
    for (int q = 0; q < 4; ++q) key[half][lt * 4 + q] = r[q];
    __syncthreads();

    // ---- 8-wide batched single-wave greedy: wave 0 -> half0, wave 4 -> half1
    const int wv = tid >> 6;
    if (wv == 0 || wv == 4) {
        const int gh = wv >> 2;
        const int w16 = lane & 15;
        const int r0 = lane >> 4;                    // my row slot (0..3)
        const u64* mrow = masks + (size_t)b * N_BOX * NWORD;
        const int nvalid = sh_nvalid[gh];
        u64 sup = 0;                                 // lanes 0..15 hold words
        int kept = 0;

        for (int bt = 0; bt < nvalid && kept < K_PER; bt += 64) {
            int t = bt + lane;
            bool in = t < nvalid;
            u64 kv = key[gh][t & (N_BOX - 1)];
            int idx = (N_BOX - 1) - (int)(u32)(kv & 0xFFFFFFFFu);
            u64 window = __ballot(in);
            while (window && kept < K_PER) {
                u64 supw = __shfl(sup, idx >> 6);
                bool sbit = (supw >> (idx & 63)) & 1ull;
                u64 alive = __ballot(in && !sbit) & window;
                if (!alive) break;
                // extract up to 8 leading alive candidates (wave-uniform)
                int ts[8], bi[8], nb = 0, tlast = 0;
                {
                    u64 am = alive;
                    #pragma unroll
                    for (int r2 = 0; r2 < 8; ++r2) {
                        if (am) {
                            ts[r2] = __ffsll((long long)am) - 1;
                            am &= am - 1; tlast = ts[r2]; nb = r2 + 1;
                        } else ts[r2] = 0;
                    }
                }
                #pragma unroll
                for (int r2 = 0; r2 < 8; ++r2) bi[r2] = __shfl(idx, ts[r2]);
                // two independent row loads (one latency round-trip):
                // rows 0..3 -> row0 (lane = s*16+word), rows 4..7 -> row1
                u64 row0 = 0, row1 = 0;
                if (r0 < nb)     row0 = mrow[(size_t)bi[r0] * NWORD + w16];
                if (r0 + 4 < nb) row1 = mrow[(size_t)bi[r0 + 4] * NWORD + w16];
                // progressive accept (greedy-exact): r accepted iff not
                // suppressed by any ACCEPTED s<r in this batch
                bool acc[8]; acc[0] = true;
                #pragma unroll
                for (int r2 = 1; r2 < 8; ++r2) {
                    bool sup_r = false;
                    if (r2 < nb) {
                        const int wq = bi[r2] >> 6;
                        #pragma unroll
                        for (int s = 0; s < 8; ++s) {
                            if (s < r2 && acc[s] && !sup_r) {
                                u64 w = (s < 4) ? __shfl(row0, s * 16 + wq)
                                                : __shfl(row1, (s - 4) * 16 + wq);
                                sup_r = (w >> (bi[r2] & 63)) & 1ull;
                            }
                        }
                    }
                    acc[r2] = (r2 < nb) && !sup_r;
                }
                // commit accepted in order; OR their rows into sup
                #pragma unroll
                for (int r2 = 0; r2 < 8; ++r2) {
                    if (r2 < nb && acc[r2] && kept < K_PER) {
                        if (lane == 0) kept_t[gh][kept] = bt + ts[r2];
                        kept++;
                        u64 w = (r2 < 4) ? __shfl(row0, r2 * 16 + w16)
                                         : __shfl(row1, (r2 - 4) * 16 + w16);
                        if (lane < NWORD) sup |= w;
                    }
                }
                window &= ~((2ull << tlast) - 1ull);
            }
        }
        if (lane == 0) sh_kept[gh] = kept;
    }
    __syncthreads();

    const int kept = sh_kept[half];
    if (lt < K_PER) {
        int ob = (b * C_CLS + c) * K_PER + lt;
        if (lt < kept) {
            u64 k = key[half][kept_t[half][lt]];
            ws_score[ob] = funord((u32)(k >> 32));
            ws_idx[ob]   = (N_BOX - 1) - (int)(u32)(k & 0xFFFFFFFFu);
        } else {
            ws_score[ob] = NEGF;
            ws_idx[ob]   = 0;
        }
    }
}

// ---------------------------------------------------------------------------
// Kernel C: one block per image, 256 threads (round-6/7 proven, verbatim).
// ---------------------------------------------------------------------------
__global__ __launch_bounds__(256) void final_topk(
        const float* __restrict__ ws_score,
        const int*   __restrict__ ws_idx,
        const float* __restrict__ boxes,    // [B, N, 1, 4]
        float* __restrict__ out)
{
    __shared__ u32 skey[NCAND];             // 32 KB — high word of each key
    __shared__ u32 hist4[256 * 4];          // 4 KB — 4 bank-spread slots/bin
    __shared__ u64 list[512];
    __shared__ int sh_sel;
    __shared__ u32 sh_need;
    __shared__ int sh_cnt, sh_valid;

    const int tid = threadIdx.x;
    const int b = blockIdx.x;
    const int base = b * NCAND;

    if (tid == 0) { sh_cnt = 0; sh_valid = 0; }
    for (int i = tid; i < NCAND; i += 256)
        skey[i] = ford(ws_score[base + i]);
    list[tid] = 0;
    list[tid + 256] = 0;
    #pragma unroll
    for (int q = 0; q < 4; ++q) hist4[q * 256 + tid] = 0;
    __syncthreads();

    u64 prefix = 0;
    u32 need = K_TOT;
    const int rounds[6] = {7, 6, 5, 4, 1, 0};
    const int slot = tid & 3;

    for (int rd = 0; rd < 6; ++rd) {
        const int d = rounds[rd];
        for (int i = tid; i < NCAND; i += 256) {
            u64 k = ((u64)skey[i] << 32) | (u32)(M_SEL - 1 - i);
            // d==7 guard: shift by 64 is UB (the round-3/4 crash)
            bool match = (d == 7) || (((k ^ prefix) >> (8 * (d + 1))) == 0);
            if (match)
                atomicAdd(&hist4[(((u32)(k >> (8 * d)) & 0xFFu) << 2) | slot], 1u);
        }
        __syncthreads();
        if (tid < 64) {
            const int l = tid;
            u32 h[4];
            #pragma unroll
            for (int q = 0; q < 4; ++q) {
                int bin = 4 * l + q;
                h[q] = hist4[bin * 4 + 0] + hist4[bin * 4 + 1]
                     + hist4[bin * 4 + 2] + hist4[bin * 4 + 3];
                hist4[bin * 4 + 0] = 0; hist4[bin * 4 + 1] = 0;
                hist4[bin * 4 + 2] = 0; hist4[bin * 4 + 3] = 0;
            }
            u32 s3 = h[3], s2 = h[2] + s3, s1 = h[1] + s2, s0 = h[0] + s1;
            u32 tot = s0, S = tot;
            #pragma unroll
            for (int off = 1; off < 64; off <<= 1) {
                u32 t = __shfl(S, (l + off) & 63);
                if (l + off < 64) S += t;
            }
            u32 T = S - tot;                 // suffix over lanes > l
            u32 sv0 = s0 + T, sv1 = s1 + T, sv2 = s2 + T, sv3 = s3 + T;
            if (sv0 >= need && sv1 < need) { sh_sel = 4*l;     sh_need = need - sv1; }
            if (sv1 >= need && sv2 < need) { sh_sel = 4*l + 1; sh_need = need - sv2; }
            if (sv2 >= need && sv3 < need) { sh_sel = 4*l + 2; sh_need = need - sv3; }
            if (sv3 >= need && T   < need) { sh_sel = 4*l + 3; sh_need = need - T;   }
        }
        __syncthreads();
        prefix |= ((u64)(u32)sh_sel) << (8 * d);
        need = sh_need;
        __syncthreads();
    }

    for (int i = tid; i < NCAND; i += 256) {
        u64 k = ((u64)skey[i] << 32) | (u32)(M_SEL - 1 - i);
        if (k >= prefix) {
            int p = atomicAdd(&sh_cnt, 1);
            if (p < 512) list[p] = k;       // defensive clamp
        }
    }
    __syncthreads();

    for (int k2 = 2; k2 <= 512; k2 <<= 1) {
        for (int j = k2 >> 1; j > 0; j >>= 1) {
            for (int i = tid; i < 512; i += 256) {
                int ixj = i ^ j;
                if (ixj > i) {
                    u64 a = list[i], q = list[ixj];
                    if (((i & k2) == 0) ? (a < q) : (a > q)) { list[i] = q; list[ixj] = a; }
                }
            }
            __syncthreads();
        }
    }

    float* out_s = out;                         // [B,300]
    float* out_b = out + B_IMG * K_TOT;         // [B,300,4]
    float* out_c = out + B_IMG * K_TOT * 5;     // [B,300]
    float* out_n = out + B_IMG * K_TOT * 6;     // [B]

    for (int i = tid; i < K_TOT; i += 256) {
        u64 k = list[i];
        float s = funord((u32)(k >> 32));
        int flat = (M_SEL - 1) - (int)(u32)(k & 0xFFFFFFFFu);
        bool valid = s > (-5e29f);              // top_s > NEG/2
        float os = 0.0f, oc = 0.0f;
        float4 ob = make_float4(0.0f, 0.0f, 0.0f, 0.0f);
        if (valid && flat < NCAND) {
            int cc = flat / K_PER;
            int n  = ws_idx[base + flat];
            float4 bb = ((const float4*)boxes)[b * N_BOX + n];
            os = s;
            oc = (float)cc;
            ob.x = fminf(fmaxf(bb.x, 0.0f), 1.0f);
            ob.y = fminf(fmaxf(bb.y, 0.0f), 1.0f);
            ob.z = fminf(fmaxf(bb.z, 0.0f), 1.0f);
            ob.w = fminf(fmaxf(bb.w, 0.0f), 1.0f);
            atomicAdd(&sh_valid, 1);
        }
        out_s[b * K_TOT + i] = os;
        ((float4*)out_b)[b * K_TOT + i] = ob;
        out_c[b * K_TOT + i] = oc;
    }
    __syncthreads();
    if (tid == 0) out_n[b] = (float)sh_valid;
}

extern "C" void kernel_launch(void* const* d_in, const int* in_sizes, int n_in,
                              void* d_out, int out_size, void* d_ws, size_t ws_size,
                              hipStream_t stream) {
    const float* scores = (const float*)d_in[0];   // [4,1024,80]
    const float* boxes  = (const float*)d_in[1];   // [4,1024,1,4]

    char* ws = (char*)d_ws;                        // 2,091,008 B used
    float* scoresT  = (float*)(ws + OFF_SCOREST);
    u64*   masks    = (u64*)  (ws + OFF_MASKS);
    float* ws_score = (float*)(ws + OFF_WSCORE);
    int*   ws_idx   = (int*)  (ws + OFF_WSIDX);

    prep_kernel<<<dim3(256 + 1280), dim3(256), 0, stream>>>(scores, boxes, masks, scoresT);
    nms_classes<<<dim3(B_IMG * (C_CLS / 2)), dim3(512), 0, stream>>>(
        scoresT, masks, ws_score, ws_idx);
    final_topk<<<dim3(B_IMG), dim3(256), 0, stream>>>(
        ws_score, ws_idx, boxes, (float*)d_out);
}

// Round 9
// 139.275 us; speedup vs baseline: 1.3099x; 1.1948x over previous
//
#include <hip/hip_runtime.h>
#include <stdint.h>

#define N_BOX 1024
#define C_CLS 80
#define B_IMG 4
#define K_PER 100
#define K_TOT 300
#define NEGF  (-1e30f)
#define NWORD 16                 // 1024 bits / 64
#define NCAND (C_CLS * K_PER)    // 8000 candidates per image
#define M_SEL 8192               // flat-index packing base for final top-k

// workspace layout (bytes) — 2,091,008 total (proven safe round 8)
#define OFF_SCOREST 0            // [B][C][N] f32          1,310,720
#define OFF_MASKS   1310720      // [B][N][NWORD] u64        524,288
#define OFF_WSCORE  1835008      // [B*C][K_PER] f32         128,000
#define OFF_WSIDX   1963008      // [B*C][K_PER] i32         128,000

typedef unsigned long long u64;
typedef unsigned int u32;

// ---- monotone float <-> ordered-uint mapping (total order, bit-exact) ----
__device__ __forceinline__ u32 ford(float f) {
    u32 u = __float_as_uint(f);
    return (u & 0x80000000u) ? ~u : (u | 0x80000000u);
}
__device__ __forceinline__ float funord(u32 o) {
    u32 u = (o & 0x80000000u) ? (o ^ 0x80000000u) : ~o;
    return __uint_as_float(u);
}

// IoU matching the numpy/jax float32 arithmetic exactly: no fma contraction.
__device__ __forceinline__ float iou_f(float4 a, float4 b) {
#pragma clang fp contract(off)
    float y1a = fminf(a.x, a.z), y2a = fmaxf(a.x, a.z);
    float x1a = fminf(a.y, a.w), x2a = fmaxf(a.y, a.w);
    float y1b = fminf(b.x, b.z), y2b = fmaxf(b.x, b.z);
    float x1b = fminf(b.y, b.w), x2b = fmaxf(b.y, b.w);
    float ih = fminf(y2a, y2b) - fmaxf(y1a, y1b); ih = fmaxf(ih, 0.0f);
    float iw = fminf(x2a, x2b) - fmaxf(x1a, x1b); iw = fmaxf(iw, 0.0f);
    float inter = ih * iw;
    float aa = (y2a - y1a) * (x2a - x1a);
    float ab = (y2b - y1b) * (x2b - x1b);
    float uni = aa + ab - inter;
    uni = fmaxf(uni, 1e-12f);
    return inter / uni;
}

// ---------------------------------------------------------------------------
// Kernel A (fused prep, proven verbatim): blocks [0,256) = per-image IoU
// bitmask matrix; blocks [256,1536) = transpose scores [B,N,C]->[B,C,N].
// ---------------------------------------------------------------------------
__global__ __launch_bounds__(256) void prep_kernel(
        const float* __restrict__ scores,   // [B, N, C]
        const float* __restrict__ boxes,    // [B, N, 1, 4]
        u64*   __restrict__ masks,          // [B, N, NWORD]
        float* __restrict__ scoresT)        // [B, C, N]
{
    __shared__ float4 bx[N_BOX];            // 16 KB (mask path); reused as tile
    const int tid = threadIdx.x;

    if (blockIdx.x < 256) {
        const int b  = blockIdx.x >> 6;
        const int rg = blockIdx.x & 63;
        for (int n = tid; n < N_BOX; n += 256)
            bx[n] = ((const float4*)boxes)[b * N_BOX + n];
        __syncthreads();

        const int r = tid >> 4;
        const int w = tid & 15;
        const int i = rg * 16 + r;
        float4 a = bx[i];
        u64 m = 0;
        const int j0 = w * 64;
        for (int jj = 0; jj < 64; ++jj) {
            int j = j0 + jj;
            if (j != i && iou_f(a, bx[j]) > 0.5f) m |= (1ull << jj);
        }
        masks[((size_t)(b * N_BOX + i)) * NWORD + w] = m;
    } else {
        float* tile = (float*)bx;               // [16][17]
        const int t = blockIdx.x - 256;
        const int b  = t / 320;
        const int rm = t % 320;
        const int n0 = (rm / 5) * 16;
        const int c0 = (rm % 5) * 16;
        const int r = tid >> 4, cc = tid & 15;
        tile[r * 17 + cc] = scores[(size_t)(b * N_BOX + n0 + r) * C_CLS + c0 + cc];
        __syncthreads();
        scoresT[(size_t)(b * C_CLS + c0 + r) * N_BOX + n0 + cc] = tile[cc * 17 + r];
    }
}

// ---------------------------------------------------------------------------
// Kernel B: one block per (image, class-PAIR), 512 threads. Register/shuffle
// bitonic sort (proven round-8). Greedy: 8-wide batches; per-batch conflict
// matrix computed with 14 PIPELINED ballots (no sequential shfl chain);
// accept resolution in per-lane VALU; sup commit via 2 shfl_xor OR-reduces.
// ---------------------------------------------------------------------------
__global__ __launch_bounds__(512) void nms_classes(
        const float* __restrict__ scoresT,  // [B, C, N]
        const u64*   __restrict__ masks,    // [B, N, NWORD]
        float* __restrict__ ws_score,       // [B*C*K_PER]
        int*   __restrict__ ws_idx)         // [B*C*K_PER]
{
    __shared__ u64 key[2][N_BOX];           // 16 KB
    __shared__ int kept_t[2][K_PER];
    __shared__ int sh_nvalid[2], sh_kept[2];

    const int tid  = threadIdx.x;
    const int half = tid >> 8;              // 0/1 = which class of the pair
    const int lt   = tid & 255;             // half-local thread id
    const int lane = tid & 63;
    const int b  = blockIdx.x / (C_CLS / 2);
    const int c  = (blockIdx.x % (C_CLS / 2)) * 2 + half;

    if (lt == 0) { sh_nvalid[half] = 0; sh_kept[half] = 0; }
    __syncthreads();

    // ---- load: thread lt owns elements v = lt*4+q (coalesced float4) ----
    u64 r[4];
    {
        const float4 s4 = ((const float4*)(scoresT + ((size_t)(b * C_CLS + c) << 10)))[lt];
        float sv[4] = {s4.x, s4.y, s4.z, s4.w};
        int lv = 0;
        #pragma unroll
        for (int q = 0; q < 4; ++q) {
            bool valid = sv[q] > 0.001f;               // SCORE_THR
            float s = valid ? sv[q] : NEGF;
            int v = lt * 4 + q;
            r[q] = ((u64)ford(s) << 32) | (u32)(N_BOX - 1 - v);  // stable ties
            lv += valid ? 1 : 0;
        }
        if (lv) atomicAdd(&sh_nvalid[half], lv);
    }

    // ---- bitonic sort, descending, 4 elems/thread (proven round-8) ----
    #define CE(a, b, d) { u64 _mx = (a) > (b) ? (a) : (b); \
                          u64 _mn = (a) > (b) ? (b) : (a); \
                          (a) = (d) ? _mx : _mn; (b) = (d) ? _mn : _mx; }
    CE(r[0], r[1], true); CE(r[2], r[3], false);

    for (int k = 4; k <= N_BOX; k <<= 1) {
        const bool d = ((lt & (k >> 2)) == 0);
        for (int j = k >> 1; j > 0; j >>= 1) {
            if (j >= 256) {                          // cross-wave: LDS stage
                __syncthreads();
                #pragma unroll
                for (int q = 0; q < 4; ++q) key[half][lt * 4 + q] = r[q];
                __syncthreads();
                const bool upper = ((lt * 4) & j) != 0;
                #pragma unroll
                for (int q = 0; q < 4; ++q) {
                    u64 pv = key[half][(lt * 4 + q) ^ j];
                    u64 mx = r[q] > pv ? r[q] : pv;
                    u64 mn = r[q] > pv ? pv : r[q];
                    r[q] = (d != upper) ? mx : mn;
                }
            } else if (j >= 4) {                     // intra-wave: shuffle
                const int dl = j >> 2;
                const bool upper = (lane & dl) != 0;
                #pragma unroll
                for (int q = 0; q < 4; ++q) {
                    u64 pv = __shfl_xor(r[q], dl);
                    u64 mx = r[q] > pv ? r[q] : pv;
                    u64 mn = r[q] > pv ? pv : r[q];
                    r[q] = (d != upper) ? mx : mn;
                }
            } else if (j == 2) {
                CE(r[0], r[2], d); CE(r[1], r[3], d);
            } else {
                CE(r[0], r[1], d); CE(r[2], r[3], d);
            }
        }
    }
    #undef CE

    __syncthreads();
    #pragma unroll
    for (int q = 0; q < 4; ++q) key[half][lt * 4 + q] = r[q];
    __syncthreads();

    // ---- 8-wide ballot-batched greedy: wave 0 -> half0, wave 4 -> half1 ----
    const int wv = tid >> 6;
    if (wv == 0 || wv == 4) {
        const int gh = wv >> 2;
        const int w16 = lane & 15;
        const int sslot = lane >> 4;                 // my row slot 0..3
        const u64* mrow = masks + (size_t)b * N_BOX * NWORD;
        const int nvalid = sh_nvalid[gh];
        u64 sup = 0;                                 // lanes 0..15 hold words
        int kept = 0;

        for (int bt = 0; bt < nvalid && kept < K_PER; bt += 64) {
            int t = bt + lane;
            bool in = t < nvalid;
            u64 kv = key[gh][t & (N_BOX - 1)];
            int idx = (N_BOX - 1) - (int)(u32)(kv & 0xFFFFFFFFu);
            u64 window = __ballot(in);
            while (window && kept < K_PER) {
                u64 supw = __shfl(sup, idx >> 6);
                bool sbit = (supw >> (idx & 63)) & 1ull;
                u64 alive = __ballot(in && !sbit) & window;
                if (!alive) break;
                // extract up to 8 leading alive candidates (wave-uniform)
                int ts[8], nb = 0, tlast = 0;
                {
                    u64 am = alive;
                    #pragma unroll
                    for (int r2 = 0; r2 < 8; ++r2) {
                        if (am) {
                            ts[r2] = __ffsll((long long)am) - 1;
                            am &= am - 1; tlast = ts[r2]; nb = r2 + 1;
                        } else ts[r2] = tlast;
                    }
                }
                int bi[8];
                #pragma unroll
                for (int r2 = 0; r2 < 8; ++r2) bi[r2] = __shfl(idx, ts[r2]);
                // rows 0..3 -> row0 (lane = s*16+word), rows 4..7 -> row1
                u64 row0 = 0, row1 = 0;
                if (sslot < nb)     row0 = mrow[(size_t)bi[sslot] * NWORD + w16];
                if (sslot + 4 < nb) row1 = mrow[(size_t)bi[sslot + 4] * NWORD + w16];
                // conflict matrix via pipelined ballots:
                // cb0[r] bit (s*16+wq) = row_s has bit bi[r]   (s = 0..3)
                // cb1[r] bit (s*16+wq) = row_{s+4} has bit bi[r]
                u64 cb0[8], cb1[8];
                #pragma unroll
                for (int r2 = 1; r2 < 8; ++r2) {
                    int wq = bi[r2] >> 6, bq = bi[r2] & 63;
                    cb0[r2] = __ballot(((row0 >> bq) & 1ull) && (w16 == wq));
                    cb1[r2] = __ballot(((row1 >> bq) & 1ull) && (w16 == wq));
                }
                // progressive accept in pure VALU (no shfl chain)
                bool acc[8]; acc[0] = true;
                #pragma unroll
                for (int r2 = 1; r2 < 8; ++r2) {
                    bool sup_r = false;
                    if (r2 < nb) {
                        int wq = bi[r2] >> 6;
                        #pragma unroll
                        for (int s = 0; s < 7; ++s) {
                            if (s < r2 && acc[s]) {
                                u64 cb = (s < 4) ? cb0[r2] : cb1[r2];
                                int bitpos = (s & 3) * 16 + wq;
                                sup_r = sup_r || (((cb >> bitpos) & 1ull) != 0);
                            }
                        }
                    }
                    acc[r2] = (r2 < nb) && !sup_r;
                }
                // commit sup: OR accepted rows via 2 shfl_xor reduces
                u64 contrib = ((sslot < nb && acc[sslot]) ? row0 : 0) |
                              ((sslot + 4 < nb && acc[sslot + 4]) ? row1 : 0);
                contrib |= __shfl_xor(contrib, 16);
                contrib |= __shfl_xor(contrib, 32);
                if (lane < NWORD) sup |= contrib;
                // record accepted in order (cap at K_PER)
                #pragma unroll
                for (int r2 = 0; r2 < 8; ++r2) {
                    if (r2 < nb && acc[r2] && kept < K_PER) {
                        if (lane == 0) kept_t[gh][kept] = bt + ts[r2];
                        kept++;
                    }
                }
                window &= ~((2ull << tlast) - 1ull);
            }
        }
        if (lane == 0) sh_kept[gh] = kept;
    }
    __syncthreads();

    const int kept = sh_kept[half];
    if (lt < K_PER) {
        int ob = (b * C_CLS + c) * K_PER + lt;
        if (lt < kept) {
            u64 k = key[half][kept_t[half][lt]];
            ws_score[ob] = funord((u32)(k >> 32));
            ws_idx[ob]   = (N_BOX - 1) - (int)(u32)(k & 0xFFFFFFFFu);
        } else {
            ws_score[ob] = NEGF;
            ws_idx[ob]   = 0;
        }
    }
}

// ---------------------------------------------------------------------------
// Kernel C: one block per image, 1024 threads. LDS-staged u32 score keys;
// byte-wise MSB radix-select (6 rounds, d==7 UB guard kept); gather exactly
// 300 winners; ONE-WAVE register bitonic sort of 512 (zero barriers).
// ---------------------------------------------------------------------------
__global__ __launch_bounds__(1024) void final_topk(
        const float* __restrict__ ws_score,
        const int*   __restrict__ ws_idx,
        const float* __restrict__ boxes,    // [B, N, 1, 4]
        float* __restrict__ out)
{
    __shared__ u32 skey[NCAND];             // 32 KB — high word of each key
    __shared__ u32 hist4[256 * 4];          // 4 KB — 4 bank-spread slots/bin
    __shared__ u64 list[512];
    __shared__ int sh_sel;
    __shared__ u32 sh_need;
    __shared__ int sh_cnt, sh_valid;

    const int tid = threadIdx.x;
    const int b = blockIdx.x;
    const int base = b * NCAND;

    if (tid == 0) { sh_cnt = 0; sh_valid = 0; }
    for (int i = tid; i < NCAND; i += 1024)
        skey[i] = ford(ws_score[base + i]);
    if (tid < 512) list[tid] = 0;
    hist4[tid] = 0;                          // 1024 slots, 1024 threads
    __syncthreads();

    u64 prefix = 0;
    u32 need = K_TOT;
    const int rounds[6] = {7, 6, 5, 4, 1, 0};
    const int slot = tid & 3;

    for (int rd = 0; rd < 6; ++rd) {
        const int d = rounds[rd];
        for (int i = tid; i < NCAND; i += 1024) {
            u64 k = ((u64)skey[i] << 32) | (u32)(M_SEL - 1 - i);
            // d==7 guard: shift by 64 is UB (the round-3/4 crash)
            bool match = (d == 7) || (((k ^ prefix) >> (8 * (d + 1))) == 0);
            if (match)
                atomicAdd(&hist4[(((u32)(k >> (8 * d)) & 0xFFu) << 2) | slot], 1u);
        }
        __syncthreads();
        if (tid < 64) {
            const int l = tid;
            u32 h[4];
            #pragma unroll
            for (int q = 0; q < 4; ++q) {
                int bin = 4 * l + q;
                h[q] = hist4[bin * 4 + 0] + hist4[bin * 4 + 1]
                     + hist4[bin * 4 + 2] + hist4[bin * 4 + 3];
                hist4[bin * 4 + 0] = 0; hist4[bin * 4 + 1] = 0;
                hist4[bin * 4 + 2] = 0; hist4[bin * 4 + 3] = 0;
            }
            u32 s3 = h[3], s2 = h[2] + s3, s1 = h[1] + s2, s0 = h[0] + s1;
            u32 tot = s0, S = tot;
            #pragma unroll
            for (int off = 1; off < 64; off <<= 1) {
                u32 t = __shfl(S, (l + off) & 63);
                if (l + off < 64) S += t;
            }
            u32 T = S - tot;                 // suffix over lanes > l
            u32 sv0 = s0 + T, sv1 = s1 + T, sv2 = s2 + T, sv3 = s3 + T;
            if (sv0 >= need && sv1 < need) { sh_sel = 4*l;     sh_need = need - sv1; }
            if (sv1 >= need && sv2 < need) { sh_sel = 4*l + 1; sh_need = need - sv2; }
            if (sv2 >= need && sv3 < need) { sh_sel = 4*l + 2; sh_need = need - sv3; }
            if (sv3 >= need && T   < need) { sh_sel = 4*l + 3; sh_need = need - T;   }
        }
        __syncthreads();
        prefix |= ((u64)(u32)sh_sel) << (8 * d);
        need = sh_need;
        __syncthreads();
    }

    for (int i = tid; i < NCAND; i += 1024) {
        u64 k = ((u64)skey[i] << 32) | (u32)(M_SEL - 1 - i);
        if (k >= prefix) {
            int p = atomicAdd(&sh_cnt, 1);
            if (p < 512) list[p] = k;       // defensive clamp
        }
    }
    __syncthreads();

    // one-wave register bitonic sort of list[512], descending (pads 0 last)
    if (tid < 64) {
        const int l = tid;
        u64 e[8];
        #pragma unroll
        for (int q = 0; q < 8; ++q) e[q] = list[l * 8 + q];
        #define CE2(a, b, dd) { u64 _mx = (a) > (b) ? (a) : (b); \
                                u64 _mn = (a) > (b) ? (b) : (a); \
                                (a) = (dd) ? _mx : _mn; (b) = (dd) ? _mn : _mx; }
        // k=2: dir = ((v&2)==0), v = l*8+q -> q&2
        CE2(e[0], e[1], true);  CE2(e[2], e[3], false);
        CE2(e[4], e[5], true);  CE2(e[6], e[7], false);
        // k=4: dir = ((v&4)==0) -> q<4
        CE2(e[0], e[2], true);  CE2(e[1], e[3], true);
        CE2(e[4], e[6], false); CE2(e[5], e[7], false);
        CE2(e[0], e[1], true);  CE2(e[2], e[3], true);
        CE2(e[4], e[5], false); CE2(e[6], e[7], false);
        for (int k = 8; k <= 512; k <<= 1) {
            const bool d = ((l & (k >> 3)) == 0);
            for (int j = k >> 1; j >= 8; j >>= 1) {
                const int dl = j >> 3;
                const bool upper = (l & dl) != 0;
                #pragma unroll
                for (int q = 0; q < 8; ++q) {
                    u64 pv = __shfl_xor(e[q], dl);
                    u64 mx = e[q] > pv ? e[q] : pv;
                    u64 mn = e[q] > pv ? pv : e[q];
                    e[q] = (d != upper) ? mx : mn;
                }
            }
            CE2(e[0], e[4], d); CE2(e[1], e[5], d);
            CE2(e[2], e[6], d); CE2(e[3], e[7], d);
            CE2(e[0], e[2], d); CE2(e[1], e[3], d);
            CE2(e[4], e[6], d); CE2(e[5], e[7], d);
            CE2(e[0], e[1], d); CE2(e[2], e[3], d);
            CE2(e[4], e[5], d); CE2(e[6], e[7], d);
        }
        #undef CE2
        #pragma unroll
        for (int q = 0; q < 8; ++q) list[l * 8 + q] = e[q];
    }
    __syncthreads();

    float* out_s = out;                         // [B,300]
    float* out_b = out + B_IMG * K_TOT;         // [B,300,4]
    float* out_c = out + B_IMG * K_TOT * 5;     // [B,300]
    float* out_n = out + B_IMG * K_TOT * 6;     // [B]

    for (int i = tid; i < K_TOT; i += 1024) {
        u64 k = list[i];
        float s = funord((u32)(k >> 32));
        int flat = (M_SEL - 1) - (int)(u32)(k & 0xFFFFFFFFu);
        bool valid = s > (-5e29f);              // top_s > NEG/2
        float os = 0.0f, oc = 0.0f;
        float4 ob = make_float4(0.0f, 0.0f, 0.0f, 0.0f);
        if (valid && flat < NCAND) {
            int cc = flat / K_PER;
            int n  = ws_idx[base + flat];
            float4 bb = ((const float4*)boxes)[b * N_BOX + n];
            os = s;
            oc = (float)cc;
            ob.x = fminf(fmaxf(bb.x, 0.0f), 1.0f);
            ob.y = fminf(fmaxf(bb.y, 0.0f), 1.0f);
            ob.z = fminf(fmaxf(bb.z, 0.0f), 1.0f);
            ob.w = fminf(fmaxf(bb.w, 0.0f), 1.0f);
            atomicAdd(&sh_valid, 1);
        }
        out_s[b * K_TOT + i] = os;
        ((float4*)out_b)[b * K_TOT + i] = ob;
        out_c[b * K_TOT + i] = oc;
    }
    __syncthreads();
    if (tid == 0) out_n[b] = (float)sh_valid;
}

extern "C" void kernel_launch(void* const* d_in, const int* in_sizes, int n_in,
                              void* d_out, int out_size, void* d_ws, size_t ws_size,
                              hipStream_t stream) {
    const float* scores = (const float*)d_in[0];   // [4,1024,80]
    const float* boxes  = (const float*)d_in[1];   // [4,1024,1,4]

    char* ws = (char*)d_ws;                        // 2,091,008 B used
    float* scoresT  = (float*)(ws + OFF_SCOREST);
    u64*   masks    = (u64*)  (ws + OFF_MASKS);
    float* ws_score = (float*)(ws + OFF_WSCORE);
    int*   ws_idx   = (int*)  (ws + OFF_WSIDX);

    prep_kernel<<<dim3(256 + 1280), dim3(256), 0, stream>>>(scores, boxes, masks, scoresT);
    nms_classes<<<dim3(B_IMG * (C_CLS / 2)), dim3(512), 0, stream>>>(
        scoresT, masks, ws_score, ws_idx);
    final_topk<<<dim3(B_IMG), dim3(1024), 0, stream>>>(
        ws_score, ws_idx, boxes, (float*)d_out);
}